// Round 11
// baseline (318.053 us; speedup 1.0000x reference)
//
#include <hip/hip_runtime.h>
#include <math.h>

// ---------------------------------------------------------------------------
// GAT 3-layer forward. GEMMs bf16-MFMA (f32 acc, global_load_lds dbuf) with
// fused alpha-dot epilogue writing addressed PARTIALS (no atomics, no init);
// aggregation = per-(node,head) wave passes, head pinned to XCD (blockIdx&3)
// so each XCD gathers one 2.5MB L2-resident h-slice; single-pass unnormalized
// softmax (logits ~12 << 88, clamp 60), 32 edges in flight per wave.
// N=10000, IN=256, HID=128, HEADS=4, OUT=128, E=320000 (+N self loops).
// ---------------------------------------------------------------------------

#define NEG_SLOPE 0.2f

typedef float f32x4 __attribute__((ext_vector_type(4)));
typedef short s16x8 __attribute__((ext_vector_type(8)));

__device__ inline unsigned short f2bf(float x) {
    unsigned int u = __builtin_bit_cast(unsigned int, x);
    u = (u + 0x7fff + ((u >> 16) & 1)) >> 16;   // RNE
    return (unsigned short)u;
}
__device__ inline float bf2f(unsigned short b) {
    return __builtin_bit_cast(float, ((unsigned int)b) << 16);
}

// ---------------- CSR build (scan + fill) ----------------

__global__ __launch_bounds__(1024) void k_scan(const int* __restrict__ counts, int N,
                                               int* __restrict__ row_ptr,
                                               int* __restrict__ cursor) {
    __shared__ int s[1024];
    int t = threadIdx.x;
    int per = (N + 1023) / 1024;
    int beg = t * per;
    int local = 0;
    for (int j = 0; j < per; ++j) {
        int i = beg + j;
        if (i < N) local += counts[i];
    }
    s[t] = local;
    __syncthreads();
    for (int off = 1; off < 1024; off <<= 1) {
        int v = (t >= off) ? s[t - off] : 0;
        __syncthreads();
        s[t] += v;
        __syncthreads();
    }
    int run = (t == 0) ? 0 : s[t - 1];
    for (int j = 0; j < per; ++j) {
        int i = beg + j;
        if (i < N) {
            row_ptr[i] = run;
            cursor[i] = run;
            run += counts[i];
        }
    }
    if (t == 1023) row_ptr[N] = s[1023];
}

__global__ void k_fill(const int* __restrict__ ei, int E, int N,
                       int* __restrict__ cursor, int* __restrict__ csr_src) {
    int e = blockIdx.x * blockDim.x + threadIdx.x;
    if (e >= E + N) return;
    int src, dst;
    if (e < E) {
        src = ei[e];
        dst = ei[(size_t)E + e];
    } else {
        src = dst = e - E;
    }
    if ((unsigned)dst >= (unsigned)N || (unsigned)src >= (unsigned)N) return;
    int slot = atomicAdd(&cursor[dst], 1);
    csr_src[slot] = src;
}

// ---------------- fused prep: edge-count | weight transpose-cast | x cast ---

__global__ __launch_bounds__(256) void k_prep(
    const int* __restrict__ ei, int E, int N, int* __restrict__ counts,
    const float* __restrict__ W0c, unsigned short* __restrict__ T0,
    const float* __restrict__ W1c, unsigned short* __restrict__ T1,
    const float* __restrict__ W2c, unsigned short* __restrict__ T2,
    const float* __restrict__ x, unsigned short* __restrict__ xo, int nx, int eb) {
    __shared__ float tile[32][33];
    int bid = blockIdx.x;
    if (bid < eb) {
        int e = bid * 256 + threadIdx.x;
        if (e >= E + N) return;
        int dst = (e < E) ? ei[(size_t)E + e] : (e - E);
        if ((unsigned)dst >= (unsigned)N) return;
        atomicAdd(&counts[dst], 1);
        return;
    }
    bid -= eb;
    if (bid < 448) {
        const float* W;
        unsigned short* T;
        int K, Nc, t;
        if (bid < 128)      { W = W0c; T = T0; K = 256; Nc = 512; t = bid; }
        else if (bid < 384) { W = W1c; T = T1; K = 512; Nc = 512; t = bid - 128; }
        else                { W = W2c; T = T2; K = 512; Nc = 128; t = bid - 384; }
        int nt = Nc / 32;
        int n0 = (t % nt) * 32, k0 = (t / nt) * 32;
        int tx = threadIdx.x % 32, ty = threadIdx.x / 32;  // 32 x 8
#pragma unroll
        for (int i = 0; i < 32; i += 8)
            tile[ty + i][tx] = W[(size_t)(k0 + ty + i) * Nc + n0 + tx];
        __syncthreads();
#pragma unroll
        for (int i = 0; i < 32; i += 8)
            T[(size_t)(n0 + ty + i) * K + k0 + tx] = f2bf(tile[tx][ty + i]);
        return;
    }
    bid -= 448;
    int i = (bid * 256 + threadIdx.x) * 4;
    if (i >= nx) return;
    if (i + 3 >= nx) {
        for (int j = i; j < nx; ++j) xo[j] = f2bf(x[j]);
        return;
    }
    float4 v = *(const float4*)(x + i);
    xo[i + 0] = f2bf(v.x);
    xo[i + 1] = f2bf(v.y);
    xo[i + 2] = f2bf(v.z);
    xo[i + 3] = f2bf(v.w);
}

// ---------------- bf16 MFMA GEMM + fused alpha-dot epilogue ----------------
// Cbf[M][N] = A[M][K](bf16) * Bt[N][K]^T(bf16).  BM=128 BN=64 BK=64, 4 waves.
// Epilogue writes PARTIAL alpha dots: asP[row][h][sub], sub=(bn>>6)&1 -- each
// (row,head,sub) written by exactly one block => no atomics, no pre-zeroing.

__global__ __launch_bounds__(256) void k_mgemm(const unsigned short* __restrict__ A,
                                               const unsigned short* __restrict__ Bt,
                                               unsigned short* __restrict__ Cbf,
                                               const float* __restrict__ a_src,
                                               const float* __restrict__ a_dst,
                                               float* __restrict__ asP,
                                               float* __restrict__ adP,
                                               int M, int N, int K, int H) {
    constexpr int BM = 128, BN = 64, BK = 64;
    constexpr int BUF = (BM + BN) * BK * 2;      // 24576 bytes
    __shared__ char lds[2][BUF];

    int tid = threadIdx.x;
    int w = tid >> 6, l = tid & 63;
    int r = l & 15, g = l >> 4;
    int bm = blockIdx.x * BM, bn = blockIdx.y * BN;

    int row8 = l >> 3;
    int slot = l & 7;

    f32x4 acc[2][4];
#pragma unroll
    for (int i = 0; i < 2; ++i)
#pragma unroll
        for (int j = 0; j < 4; ++j) acc[i][j] = (f32x4)0.f;

    auto stage = [&](int buf, int k0) {
        char* Asl = lds[buf];
        char* Bsl = lds[buf] + BM * BK * 2;
#pragma unroll
        for (int p = 0; p < 4; ++p) {
            int base_row = p * 32 + w * 8;
            int row = base_row + row8;
            const unsigned short* gp =
                A + (size_t)(bm + row) * K + k0 + ((slot ^ (row & 7)) * 8);
            __builtin_amdgcn_global_load_lds(
                (const __attribute__((address_space(1))) void*)gp,
                (__attribute__((address_space(3))) void*)(Asl + base_row * (BK * 2)),
                16, 0, 0);
        }
#pragma unroll
        for (int p = 0; p < 2; ++p) {
            int base_row = p * 32 + w * 8;
            int row = base_row + row8;
            const unsigned short* gp =
                Bt + (size_t)(bn + row) * K + k0 + ((slot ^ (row & 7)) * 8);
            __builtin_amdgcn_global_load_lds(
                (const __attribute__((address_space(1))) void*)gp,
                (__attribute__((address_space(3))) void*)(Bsl + base_row * (BK * 2)),
                16, 0, 0);
        }
    };

    int nt = K >> 6;
    stage(0, 0);
    __syncthreads();

    int cur = 0;
    for (int t = 0; t < nt; ++t) {
        if (t + 1 < nt) stage(cur ^ 1, (t + 1) * BK);

        char* Asl = lds[cur];
        char* Bsl = lds[cur] + BM * BK * 2;
#pragma unroll
        for (int kk = 0; kk < 2; ++kk) {
            int kb = kk * 64 + g * 16;
            s16x8 af[2], bfr[4];
#pragma unroll
            for (int mf = 0; mf < 2; ++mf) {
                int m = w * 32 + mf * 16 + r;
                int byte = (m * (BK * 2) + kb) ^ ((m & 7) << 4);
                af[mf] = *(const s16x8*)(Asl + byte);
            }
#pragma unroll
            for (int nf = 0; nf < 4; ++nf) {
                int n = nf * 16 + r;
                int byte = (n * (BK * 2) + kb) ^ ((n & 7) << 4);
                bfr[nf] = *(const s16x8*)(Bsl + byte);
            }
#pragma unroll
            for (int mf = 0; mf < 2; ++mf)
#pragma unroll
                for (int nf = 0; nf < 4; ++nf)
                    acc[mf][nf] = __builtin_amdgcn_mfma_f32_16x16x32_bf16(
                        af[mf], bfr[nf], acc[mf][nf], 0, 0, 0);
        }
        __syncthreads();
        cur ^= 1;
    }

    // C store
#pragma unroll
    for (int mf = 0; mf < 2; ++mf) {
#pragma unroll
        for (int nf = 0; nf < 4; ++nf) {
#pragma unroll
            for (int j = 0; j < 4; ++j) {
                int grow = bm + w * 32 + mf * 16 + g * 4 + j;
                if (grow < M)
                    Cbf[(size_t)grow * N + bn + nf * 16 + r] = f2bf(acc[mf][nf][j]);
            }
        }
    }

    // fused alpha partials (this block's head / sub-slot)
    int hh = bn >> 7;          // C=128; BN=64 keeps a block within one head
    int sub = (bn >> 6) & 1;   // which 64-col half of the head
    int cb = bn & 127;
    float a1v[4], a2v[4];
#pragma unroll
    for (int nf = 0; nf < 4; ++nf) {
        int ch = cb + nf * 16 + r;
        a1v[nf] = a_src[hh * 128 + ch];
        a2v[nf] = a_dst[hh * 128 + ch];
    }
#pragma unroll
    for (int mf = 0; mf < 2; ++mf) {
#pragma unroll
        for (int j = 0; j < 4; ++j) {
            float p1 = 0.f, p2 = 0.f;
#pragma unroll
            for (int nf = 0; nf < 4; ++nf) {
                p1 = fmaf(acc[mf][nf][j], a1v[nf], p1);
                p2 = fmaf(acc[mf][nf][j], a2v[nf], p2);
            }
#pragma unroll
            for (int off = 1; off < 16; off <<= 1) {
                p1 += __shfl_xor(p1, off);
                p2 += __shfl_xor(p2, off);
            }
            int grow = bm + w * 32 + mf * 16 + g * 4 + j;
            if (r == 0 && grow < M) {
                size_t ix = (size_t)grow * (2 * H) + hh * 2 + sub;
                asP[ix] = p1;
                adP[ix] = p2;
            }
        }
    }
}

// ---------------- per-(node,head) fused softmax + aggregation --------------
// Wave = 4 edge-slots x 16 lanes; 32 edges in flight per iteration. head =
// blockIdx&3 pins each XCD to ONE 2.5MB h-slice (L2-resident). Alpha read as
// float2 partial-pair sum. Unnormalized single-pass softmax, normalize at end.

template <int H, bool DO_ELU, bool OUT_BF>
__global__ __launch_bounds__(256) void k_agghead(
    const unsigned short* __restrict__ hbf, const float* __restrict__ asP,
    const float* __restrict__ adP, const int* __restrict__ row_ptr,
    const int* __restrict__ csr_src, const float* __restrict__ bias,
    float* __restrict__ outf, unsigned short* __restrict__ outb, int N) {
    constexpr int HC = H * 128;
    int bid = blockIdx.x;
    int q, grp;
    if (H == 4) { q = bid & 3; grp = bid >> 2; }
    else        { q = 0; grp = bid; }
    int wv = threadIdx.x >> 6;
    int n = grp * 4 + wv;
    if (n >= N) return;
    int l = threadIdx.x & 63;
    int eg = l >> 4;      // edge slot 0..3
    int r = l & 15;       // 16B lane-slot within 256B row slice
    int beg = row_ptr[n], end = row_ptr[n + 1];
    float2 adv = *(const float2*)(adP + (size_t)n * (2 * H) + q * 2);
    float adq = adv.x + adv.y;

    float den = 0.f;
    float acc[8];
#pragma unroll
    for (int k = 0; k < 8; ++k) acc[k] = 0.f;

    const unsigned short* hq = hbf + q * 128 + r * 8;

    for (int e0 = beg; e0 < end; e0 += 32) {
        int s[8];
        float msk[8];
#pragma unroll
        for (int u = 0; u < 8; ++u) {
            int e = e0 + u * 4 + eg;
            s[u] = csr_src[e < end ? e : end - 1];
            msk[u] = (e < end) ? 1.f : 0.f;
        }
        s16x8 v[8];
#pragma unroll
        for (int u = 0; u < 8; ++u)
            v[u] = *(const s16x8*)(hq + (size_t)s[u] * HC);
        float wg[8];
#pragma unroll
        for (int u = 0; u < 8; ++u) {
            float2 asv = *(const float2*)(asP + (size_t)s[u] * (2 * H) + q * 2);
            float lg = asv.x + asv.y + adq;
            lg = (lg > 0.f) ? lg : NEG_SLOPE * lg;
            float ex = __expf(fminf(lg, 60.f)) * msk[u];
            den += ex;
            wg[u] = ex;
        }
#pragma unroll
        for (int u = 0; u < 8; ++u)
#pragma unroll
            for (int k = 0; k < 8; ++k)
                acc[k] = fmaf(wg[u], bf2f((unsigned short)v[u][k]), acc[k]);
    }

    // reduce across the 4 edge-slot groups (lane^16, lane^32)
#pragma unroll
    for (int k = 0; k < 8; ++k) {
        acc[k] += __shfl_xor(acc[k], 16);
        acc[k] += __shfl_xor(acc[k], 32);
    }
    den += __shfl_xor(den, 16);
    den += __shfl_xor(den, 32);

    if (eg == 0) {
        float rden = 1.f / (den + 1e-16f);
        int chb = q * 128 + r * 8;
        if (OUT_BF) {
            s16x8 o;
#pragma unroll
            for (int k = 0; k < 8; ++k) {
                float vv = fmaf(acc[k], rden, bias[chb + k]);
                if (DO_ELU) vv = (vv > 0.f) ? vv : (__expf(vv) - 1.f);
                o[k] = (short)f2bf(vv);
            }
            *(s16x8*)(outb + (size_t)n * HC + chb) = o;
        } else {
            f32x4 o0, o1;
#pragma unroll
            for (int k = 0; k < 8; ++k) {
                float vv = fmaf(acc[k], rden, bias[chb + k]);
                if (DO_ELU) vv = (vv > 0.f) ? vv : (__expf(vv) - 1.f);
                if (k < 4) o0[k] = vv; else o1[k - 4] = vv;
            }
            *(f32x4*)(outf + (size_t)n * HC + chb) = o0;
            *(f32x4*)(outf + (size_t)n * HC + chb + 4) = o1;
        }
    }
}

// ---------------------------------------------------------------------------

extern "C" void kernel_launch(void* const* d_in, const int* in_sizes, int n_in,
                              void* d_out, int out_size, void* d_ws, size_t ws_size,
                              hipStream_t stream) {
    const float* x = (const float*)d_in[0];
    const int* ei = (const int*)d_in[1];
    const float* W0 = (const float*)d_in[2];
    const float* as0 = (const float*)d_in[3];
    const float* ad0 = (const float*)d_in[4];
    const float* b0 = (const float*)d_in[5];
    const float* W1 = (const float*)d_in[6];
    const float* as1 = (const float*)d_in[7];
    const float* ad1 = (const float*)d_in[8];
    const float* b1 = (const float*)d_in[9];
    const float* W2 = (const float*)d_in[10];
    const float* as2 = (const float*)d_in[11];
    const float* ad2 = (const float*)d_in[12];
    const float* b2 = (const float*)d_in[13];

    const int N = in_sizes[0] / 256;   // 10000
    const int E = in_sizes[1] / 2;     // 320000
    const int Etot = E + N;
    const int IN_CH = 256, HEADS = 4, OUT_CH = 128;
    const int HC = HEADS * 128;        // 512

    // workspace: [counts N][asP 8N][adP 8N][row_ptr N+1][cursor N][csr Etot][bf16...]
    int* counts = (int*)d_ws;
    float* asP = (float*)(counts + N);      // N * 2H  (H<=4 -> 8N)
    float* adP = asP + 8 * (size_t)N;       // 8N
    int* row_ptr = (int*)(adP + 8 * (size_t)N);  // N+1
    int* cursor = row_ptr + (N + 1);
    int* csr_src = cursor + N;              // Etot
    uintptr_t p = (uintptr_t)(csr_src + Etot);
    p = (p + 15) & ~(uintptr_t)15;
    unsigned short* abf = (unsigned short*)p;        // N*512 bf16 (GEMM A / agg out)
    unsigned short* hbf = abf + (size_t)N * HC;      // N*512 bf16 (GEMM out)
    unsigned short* wt0 = hbf + (size_t)N * HC;      // 512*256
    unsigned short* wt1 = wt0 + (size_t)HC * IN_CH;  // 512*512
    unsigned short* wt2 = wt1 + (size_t)HC * HC;     // 128*512

    // ---- zero counts, then prep + CSR ----
    hipMemsetAsync(counts, 0, (size_t)N * sizeof(int), stream);
    int eb = (Etot + 255) / 256;
    int nx = N * IN_CH;
    int ab = (nx / 4 + 255) / 256;
    k_prep<<<eb + 448 + ab, 256, 0, stream>>>(ei, E, N, counts, W0, wt0, W1, wt1,
                                              W2, wt2, x, abf, nx, eb);
    k_scan<<<1, 1024, 0, stream>>>(counts, N, row_ptr, cursor);
    k_fill<<<(Etot + 255) / 256, 256, 0, stream>>>(ei, E, N, cursor, csr_src);

    // ---- layer 0: x[N,256] @ W0[256,512] ----
    {
        dim3 grid((N + 127) / 128, HC / 64);
        k_mgemm<<<grid, 256, 0, stream>>>(abf, wt0, hbf, as0, ad0, asP, adP,
                                          N, HC, IN_CH, HEADS);
        k_agghead<4, true, true><<<N, 256, 0, stream>>>(
            hbf, asP, adP, row_ptr, csr_src, b0, nullptr, abf, N);
    }
    // ---- layer 1: abf[N,512] @ W1[512,512] ----
    {
        dim3 grid((N + 127) / 128, HC / 64);
        k_mgemm<<<grid, 256, 0, stream>>>(abf, wt1, hbf, as1, ad1, asP, adP,
                                          N, HC, HC, HEADS);
        k_agghead<4, true, true><<<N, 256, 0, stream>>>(
            hbf, asP, adP, row_ptr, csr_src, b1, nullptr, abf, N);
    }
    // ---- layer 2: abf[N,512] @ W2[512,128], heads=1, no ELU ----
    {
        dim3 grid((N + 127) / 128, OUT_CH / 64);
        k_mgemm<<<grid, 256, 0, stream>>>(abf, wt2, hbf, as2, ad2, asP, adP,
                                          N, OUT_CH, HC, 1);
        k_agghead<1, false, false><<<(N + 3) / 4, 256, 0, stream>>>(
            hbf, asP, adP, row_ptr, csr_src, b2, (float*)d_out, nullptr, N);
    }
}

// Round 12
// 290.298 us; speedup vs baseline: 1.0956x; 1.0956x over previous
//
#include <hip/hip_runtime.h>
#include <math.h>

// ---------------------------------------------------------------------------
// GAT 3-layer forward. GEMMs bf16-MFMA (f32 acc, global_load_lds dbuf) with
// fused alpha-dot epilogue writing addressed PARTIALS (no atomics, no init);
// aggregation = per-(node,head) wave passes, head pinned to XCD (blockIdx&3)
// so each XCD gathers one 2.5MB L2-resident h-slice; single-pass unnormalized
// softmax (logits ~12 << 88, clamp 60), 16 edges per wave iteration (32-edge
// unroll regressed: masked-tail waste ~94% at mean deg 33 -- R11 lesson).
// N=10000, IN=256, HID=128, HEADS=4, OUT=128, E=320000 (+N self loops).
// ---------------------------------------------------------------------------

#define NEG_SLOPE 0.2f

typedef float f32x4 __attribute__((ext_vector_type(4)));
typedef short s16x8 __attribute__((ext_vector_type(8)));

__device__ inline unsigned short f2bf(float x) {
    unsigned int u = __builtin_bit_cast(unsigned int, x);
    u = (u + 0x7fff + ((u >> 16) & 1)) >> 16;   // RNE
    return (unsigned short)u;
}
__device__ inline float bf2f(unsigned short b) {
    return __builtin_bit_cast(float, ((unsigned int)b) << 16);
}

// ---------------- CSR build (scan + fill) ----------------

__global__ __launch_bounds__(1024) void k_scan(const int* __restrict__ counts, int N,
                                               int* __restrict__ row_ptr,
                                               int* __restrict__ cursor) {
    __shared__ int s[1024];
    int t = threadIdx.x;
    int per = (N + 1023) / 1024;
    int beg = t * per;
    int local = 0;
    for (int j = 0; j < per; ++j) {
        int i = beg + j;
        if (i < N) local += counts[i];
    }
    s[t] = local;
    __syncthreads();
    for (int off = 1; off < 1024; off <<= 1) {
        int v = (t >= off) ? s[t - off] : 0;
        __syncthreads();
        s[t] += v;
        __syncthreads();
    }
    int run = (t == 0) ? 0 : s[t - 1];
    for (int j = 0; j < per; ++j) {
        int i = beg + j;
        if (i < N) {
            row_ptr[i] = run;
            cursor[i] = run;
            run += counts[i];
        }
    }
    if (t == 1023) row_ptr[N] = s[1023];
}

__global__ void k_fill(const int* __restrict__ ei, int E, int N,
                       int* __restrict__ cursor, int* __restrict__ csr_src) {
    int e = blockIdx.x * blockDim.x + threadIdx.x;
    if (e >= E + N) return;
    int src, dst;
    if (e < E) {
        src = ei[e];
        dst = ei[(size_t)E + e];
    } else {
        src = dst = e - E;
    }
    if ((unsigned)dst >= (unsigned)N || (unsigned)src >= (unsigned)N) return;
    int slot = atomicAdd(&cursor[dst], 1);
    csr_src[slot] = src;
}

// ---------------- fused prep: edge-count | weight transpose-cast | x cast ---

__global__ __launch_bounds__(256) void k_prep(
    const int* __restrict__ ei, int E, int N, int* __restrict__ counts,
    const float* __restrict__ W0c, unsigned short* __restrict__ T0,
    const float* __restrict__ W1c, unsigned short* __restrict__ T1,
    const float* __restrict__ W2c, unsigned short* __restrict__ T2,
    const float* __restrict__ x, unsigned short* __restrict__ xo, int nx, int eb) {
    __shared__ float tile[32][33];
    int bid = blockIdx.x;
    if (bid < eb) {
        int e = bid * 256 + threadIdx.x;
        if (e >= E + N) return;
        int dst = (e < E) ? ei[(size_t)E + e] : (e - E);
        if ((unsigned)dst >= (unsigned)N) return;
        atomicAdd(&counts[dst], 1);
        return;
    }
    bid -= eb;
    if (bid < 448) {
        const float* W;
        unsigned short* T;
        int K, Nc, t;
        if (bid < 128)      { W = W0c; T = T0; K = 256; Nc = 512; t = bid; }
        else if (bid < 384) { W = W1c; T = T1; K = 512; Nc = 512; t = bid - 128; }
        else                { W = W2c; T = T2; K = 512; Nc = 128; t = bid - 384; }
        int nt = Nc / 32;
        int n0 = (t % nt) * 32, k0 = (t / nt) * 32;
        int tx = threadIdx.x % 32, ty = threadIdx.x / 32;  // 32 x 8
#pragma unroll
        for (int i = 0; i < 32; i += 8)
            tile[ty + i][tx] = W[(size_t)(k0 + ty + i) * Nc + n0 + tx];
        __syncthreads();
#pragma unroll
        for (int i = 0; i < 32; i += 8)
            T[(size_t)(n0 + ty + i) * K + k0 + tx] = f2bf(tile[tx][ty + i]);
        return;
    }
    bid -= 448;
    int i = (bid * 256 + threadIdx.x) * 4;
    if (i >= nx) return;
    if (i + 3 >= nx) {
        for (int j = i; j < nx; ++j) xo[j] = f2bf(x[j]);
        return;
    }
    float4 v = *(const float4*)(x + i);
    xo[i + 0] = f2bf(v.x);
    xo[i + 1] = f2bf(v.y);
    xo[i + 2] = f2bf(v.z);
    xo[i + 3] = f2bf(v.w);
}

// ---------------- bf16 MFMA GEMM + fused alpha-dot epilogue ----------------
// Cbf[M][N] = A[M][K](bf16) * Bt[N][K]^T(bf16).  BM=128 BN=64 BK=64, 4 waves.
// Epilogue writes PARTIAL alpha dots: asP[row][h][sub], sub=(bn>>6)&1 -- each
// (row,head,sub) written by exactly one block => no atomics, no pre-zeroing.

__global__ __launch_bounds__(256) void k_mgemm(const unsigned short* __restrict__ A,
                                               const unsigned short* __restrict__ Bt,
                                               unsigned short* __restrict__ Cbf,
                                               const float* __restrict__ a_src,
                                               const float* __restrict__ a_dst,
                                               float* __restrict__ asP,
                                               float* __restrict__ adP,
                                               int M, int N, int K, int H) {
    constexpr int BM = 128, BN = 64, BK = 64;
    constexpr int BUF = (BM + BN) * BK * 2;      // 24576 bytes
    __shared__ char lds[2][BUF];

    int tid = threadIdx.x;
    int w = tid >> 6, l = tid & 63;
    int r = l & 15, g = l >> 4;
    int bm = blockIdx.x * BM, bn = blockIdx.y * BN;

    int row8 = l >> 3;
    int slot = l & 7;

    f32x4 acc[2][4];
#pragma unroll
    for (int i = 0; i < 2; ++i)
#pragma unroll
        for (int j = 0; j < 4; ++j) acc[i][j] = (f32x4)0.f;

    auto stage = [&](int buf, int k0) {
        char* Asl = lds[buf];
        char* Bsl = lds[buf] + BM * BK * 2;
#pragma unroll
        for (int p = 0; p < 4; ++p) {
            int base_row = p * 32 + w * 8;
            int row = base_row + row8;
            const unsigned short* gp =
                A + (size_t)(bm + row) * K + k0 + ((slot ^ (row & 7)) * 8);
            __builtin_amdgcn_global_load_lds(
                (const __attribute__((address_space(1))) void*)gp,
                (__attribute__((address_space(3))) void*)(Asl + base_row * (BK * 2)),
                16, 0, 0);
        }
#pragma unroll
        for (int p = 0; p < 2; ++p) {
            int base_row = p * 32 + w * 8;
            int row = base_row + row8;
            const unsigned short* gp =
                Bt + (size_t)(bn + row) * K + k0 + ((slot ^ (row & 7)) * 8);
            __builtin_amdgcn_global_load_lds(
                (const __attribute__((address_space(1))) void*)gp,
                (__attribute__((address_space(3))) void*)(Bsl + base_row * (BK * 2)),
                16, 0, 0);
        }
    };

    int nt = K >> 6;
    stage(0, 0);
    __syncthreads();

    int cur = 0;
    for (int t = 0; t < nt; ++t) {
        if (t + 1 < nt) stage(cur ^ 1, (t + 1) * BK);

        char* Asl = lds[cur];
        char* Bsl = lds[cur] + BM * BK * 2;
#pragma unroll
        for (int kk = 0; kk < 2; ++kk) {
            int kb = kk * 64 + g * 16;
            s16x8 af[2], bfr[4];
#pragma unroll
            for (int mf = 0; mf < 2; ++mf) {
                int m = w * 32 + mf * 16 + r;
                int byte = (m * (BK * 2) + kb) ^ ((m & 7) << 4);
                af[mf] = *(const s16x8*)(Asl + byte);
            }
#pragma unroll
            for (int nf = 0; nf < 4; ++nf) {
                int n = nf * 16 + r;
                int byte = (n * (BK * 2) + kb) ^ ((n & 7) << 4);
                bfr[nf] = *(const s16x8*)(Bsl + byte);
            }
#pragma unroll
            for (int mf = 0; mf < 2; ++mf)
#pragma unroll
                for (int nf = 0; nf < 4; ++nf)
                    acc[mf][nf] = __builtin_amdgcn_mfma_f32_16x16x32_bf16(
                        af[mf], bfr[nf], acc[mf][nf], 0, 0, 0);
        }
        __syncthreads();
        cur ^= 1;
    }

    // C store
#pragma unroll
    for (int mf = 0; mf < 2; ++mf) {
#pragma unroll
        for (int nf = 0; nf < 4; ++nf) {
#pragma unroll
            for (int j = 0; j < 4; ++j) {
                int grow = bm + w * 32 + mf * 16 + g * 4 + j;
                if (grow < M)
                    Cbf[(size_t)grow * N + bn + nf * 16 + r] = f2bf(acc[mf][nf][j]);
            }
        }
    }

    // fused alpha partials (this block's head / sub-slot)
    int hh = bn >> 7;          // C=128; BN=64 keeps a block within one head
    int sub = (bn >> 6) & 1;   // which 64-col half of the head
    int cb = bn & 127;
    float a1v[4], a2v[4];
#pragma unroll
    for (int nf = 0; nf < 4; ++nf) {
        int ch = cb + nf * 16 + r;
        a1v[nf] = a_src[hh * 128 + ch];
        a2v[nf] = a_dst[hh * 128 + ch];
    }
#pragma unroll
    for (int mf = 0; mf < 2; ++mf) {
#pragma unroll
        for (int j = 0; j < 4; ++j) {
            float p1 = 0.f, p2 = 0.f;
#pragma unroll
            for (int nf = 0; nf < 4; ++nf) {
                p1 = fmaf(acc[mf][nf][j], a1v[nf], p1);
                p2 = fmaf(acc[mf][nf][j], a2v[nf], p2);
            }
#pragma unroll
            for (int off = 1; off < 16; off <<= 1) {
                p1 += __shfl_xor(p1, off);
                p2 += __shfl_xor(p2, off);
            }
            int grow = bm + w * 32 + mf * 16 + g * 4 + j;
            if (r == 0 && grow < M) {
                size_t ix = (size_t)grow * (2 * H) + hh * 2 + sub;
                asP[ix] = p1;
                adP[ix] = p2;
            }
        }
    }
}

// ---------------- per-(node,head) fused softmax + aggregation --------------
// Wave = 4 edge-slots x 16 lanes; 16 edges per iteration (4/slot). head =
// blockIdx&3 pins each XCD to ONE 2.5MB h-slice (L2-resident). Alpha read as
// float2 partial-pair sum. Unnormalized single-pass softmax, normalize at end.

template <int H, bool DO_ELU, bool OUT_BF>
__global__ __launch_bounds__(256) void k_agghead(
    const unsigned short* __restrict__ hbf, const float* __restrict__ asP,
    const float* __restrict__ adP, const int* __restrict__ row_ptr,
    const int* __restrict__ csr_src, const float* __restrict__ bias,
    float* __restrict__ outf, unsigned short* __restrict__ outb, int N) {
    constexpr int HC = H * 128;
    int bid = blockIdx.x;
    int q, grp;
    if (H == 4) { q = bid & 3; grp = bid >> 2; }
    else        { q = 0; grp = bid; }
    int wv = threadIdx.x >> 6;
    int n = grp * 4 + wv;
    if (n >= N) return;
    int l = threadIdx.x & 63;
    int eg = l >> 4;      // edge slot 0..3
    int r = l & 15;       // 16B lane-slot within 256B row slice
    int beg = row_ptr[n], end = row_ptr[n + 1];
    float2 adv = *(const float2*)(adP + (size_t)n * (2 * H) + q * 2);
    float adq = adv.x + adv.y;

    float den = 0.f;
    float acc[8];
#pragma unroll
    for (int k = 0; k < 8; ++k) acc[k] = 0.f;

    const unsigned short* hq = hbf + q * 128 + r * 8;

    for (int e0 = beg; e0 < end; e0 += 16) {
        int s[4];
        float msk[4];
#pragma unroll
        for (int u = 0; u < 4; ++u) {
            int e = e0 + u * 4 + eg;
            s[u] = csr_src[e < end ? e : end - 1];
            msk[u] = (e < end) ? 1.f : 0.f;
        }
        s16x8 v[4];
#pragma unroll
        for (int u = 0; u < 4; ++u)
            v[u] = *(const s16x8*)(hq + (size_t)s[u] * HC);
        float wg[4];
#pragma unroll
        for (int u = 0; u < 4; ++u) {
            float2 asv = *(const float2*)(asP + (size_t)s[u] * (2 * H) + q * 2);
            float lg = asv.x + asv.y + adq;
            lg = (lg > 0.f) ? lg : NEG_SLOPE * lg;
            float ex = __expf(fminf(lg, 60.f)) * msk[u];
            den += ex;
            wg[u] = ex;
        }
#pragma unroll
        for (int u = 0; u < 4; ++u)
#pragma unroll
            for (int k = 0; k < 8; ++k)
                acc[k] = fmaf(wg[u], bf2f((unsigned short)v[u][k]), acc[k]);
    }

    // reduce across the 4 edge-slot groups (lane^16, lane^32)
#pragma unroll
    for (int k = 0; k < 8; ++k) {
        acc[k] += __shfl_xor(acc[k], 16);
        acc[k] += __shfl_xor(acc[k], 32);
    }
    den += __shfl_xor(den, 16);
    den += __shfl_xor(den, 32);

    if (eg == 0) {
        float rden = 1.f / (den + 1e-16f);
        int chb = q * 128 + r * 8;
        if (OUT_BF) {
            s16x8 o;
#pragma unroll
            for (int k = 0; k < 8; ++k) {
                float vv = fmaf(acc[k], rden, bias[chb + k]);
                if (DO_ELU) vv = (vv > 0.f) ? vv : (__expf(vv) - 1.f);
                o[k] = (short)f2bf(vv);
            }
            *(s16x8*)(outb + (size_t)n * HC + chb) = o;
        } else {
            f32x4 o0, o1;
#pragma unroll
            for (int k = 0; k < 8; ++k) {
                float vv = fmaf(acc[k], rden, bias[chb + k]);
                if (DO_ELU) vv = (vv > 0.f) ? vv : (__expf(vv) - 1.f);
                if (k < 4) o0[k] = vv; else o1[k - 4] = vv;
            }
            *(f32x4*)(outf + (size_t)n * HC + chb) = o0;
            *(f32x4*)(outf + (size_t)n * HC + chb + 4) = o1;
        }
    }
}

// ---------------------------------------------------------------------------

extern "C" void kernel_launch(void* const* d_in, const int* in_sizes, int n_in,
                              void* d_out, int out_size, void* d_ws, size_t ws_size,
                              hipStream_t stream) {
    const float* x = (const float*)d_in[0];
    const int* ei = (const int*)d_in[1];
    const float* W0 = (const float*)d_in[2];
    const float* as0 = (const float*)d_in[3];
    const float* ad0 = (const float*)d_in[4];
    const float* b0 = (const float*)d_in[5];
    const float* W1 = (const float*)d_in[6];
    const float* as1 = (const float*)d_in[7];
    const float* ad1 = (const float*)d_in[8];
    const float* b1 = (const float*)d_in[9];
    const float* W2 = (const float*)d_in[10];
    const float* as2 = (const float*)d_in[11];
    const float* ad2 = (const float*)d_in[12];
    const float* b2 = (const float*)d_in[13];

    const int N = in_sizes[0] / 256;   // 10000
    const int E = in_sizes[1] / 2;     // 320000
    const int Etot = E + N;
    const int IN_CH = 256, HEADS = 4, OUT_CH = 128;
    const int HC = HEADS * 128;        // 512

    // workspace: [counts N][asP 8N][adP 8N][row_ptr N+1][cursor N][csr Etot][bf16...]
    int* counts = (int*)d_ws;
    float* asP = (float*)(counts + N);      // N * 2H  (H<=4 -> 8N)
    float* adP = asP + 8 * (size_t)N;       // 8N
    int* row_ptr = (int*)(adP + 8 * (size_t)N);  // N+1
    int* cursor = row_ptr + (N + 1);
    int* csr_src = cursor + N;              // Etot
    uintptr_t p = (uintptr_t)(csr_src + Etot);
    p = (p + 15) & ~(uintptr_t)15;
    unsigned short* abf = (unsigned short*)p;        // N*512 bf16 (GEMM A / agg out)
    unsigned short* hbf = abf + (size_t)N * HC;      // N*512 bf16 (GEMM out)
    unsigned short* wt0 = hbf + (size_t)N * HC;      // 512*256
    unsigned short* wt1 = wt0 + (size_t)HC * IN_CH;  // 512*512
    unsigned short* wt2 = wt1 + (size_t)HC * HC;     // 128*512

    // ---- zero counts, then prep + CSR ----
    hipMemsetAsync(counts, 0, (size_t)N * sizeof(int), stream);
    int eb = (Etot + 255) / 256;
    int nx = N * IN_CH;
    int ab = (nx / 4 + 255) / 256;
    k_prep<<<eb + 448 + ab, 256, 0, stream>>>(ei, E, N, counts, W0, wt0, W1, wt1,
                                              W2, wt2, x, abf, nx, eb);
    k_scan<<<1, 1024, 0, stream>>>(counts, N, row_ptr, cursor);
    k_fill<<<(Etot + 255) / 256, 256, 0, stream>>>(ei, E, N, cursor, csr_src);

    // ---- layer 0: x[N,256] @ W0[256,512] ----
    {
        dim3 grid((N + 127) / 128, HC / 64);
        k_mgemm<<<grid, 256, 0, stream>>>(abf, wt0, hbf, as0, ad0, asP, adP,
                                          N, HC, IN_CH, HEADS);
        k_agghead<4, true, true><<<N, 256, 0, stream>>>(
            hbf, asP, adP, row_ptr, csr_src, b0, nullptr, abf, N);
    }
    // ---- layer 1: abf[N,512] @ W1[512,512] ----
    {
        dim3 grid((N + 127) / 128, HC / 64);
        k_mgemm<<<grid, 256, 0, stream>>>(abf, wt1, hbf, as1, ad1, asP, adP,
                                          N, HC, HC, HEADS);
        k_agghead<4, true, true><<<N, 256, 0, stream>>>(
            hbf, asP, adP, row_ptr, csr_src, b1, nullptr, abf, N);
    }
    // ---- layer 2: abf[N,512] @ W2[512,128], heads=1, no ELU ----
    {
        dim3 grid((N + 127) / 128, OUT_CH / 64);
        k_mgemm<<<grid, 256, 0, stream>>>(abf, wt2, hbf, as2, ad2, asP, adP,
                                          N, OUT_CH, HC, 1);
        k_agghead<1, false, false><<<(N + 3) / 4, 256, 0, stream>>>(
            hbf, asP, adP, row_ptr, csr_src, b2, (float*)d_out, nullptr, N);
    }
}